// Round 3
// baseline (470.938 us; speedup 1.0000x reference)
//
#include <hip/hip_runtime.h>

#define IN_C   256
#define OUT_C  512
#define WIDTH  56
#define HW     3136        // 56*56
#define KTOT   2304        // IN_C*9
#define NF     64
#define NU     448         // OUT_C - NF
#define NB     32
#define NGRP   8           // ic groups of 32
#define TN     64          // pixels per block (3136 = 49*64 exactly)
#define NTILE  49
#define SROWS  192         // staged slab rows (178 needed = TN + 2*57, pad to 3*64)

typedef __bf16 bf16x8 __attribute__((ext_vector_type(8)));
typedef float  f32x4  __attribute__((ext_vector_type(4)));

// ---------------- kernel 1: [blocks 0..1567] transpose+pool   [1568..2079] weight frag ----
// xpose: x[b][ic][px] f32 -> xT[b][px][ic] bf16 ; partial[(b*49+tile)*256+ic] = tile ch-sum
// wfrag: w[oc][ic][tap] f32 -> wf[oc][(ic>>5)*9+tap][ic&31] bf16 (sel-independent)
__global__ __launch_bounds__(256) void prep_kernel(const float* __restrict__ x,
                                                   __bf16* __restrict__ xT,
                                                   float* __restrict__ partial,
                                                   const float* __restrict__ wsrc,
                                                   __bf16* __restrict__ wf) {
    __shared__ float smem[64 * 65 + IN_C];      // xpose: tl[64][65]+plsum / wfrag: sm[2304]
    int id  = blockIdx.x;
    int tid = threadIdx.x;
    if (id < NB * NTILE) {
        float (*tl)[65] = (float (*)[65])smem;
        float* plsum = smem + 64 * 65;
        int b = id / NTILE, tile = id - b * NTILE;
        int ptile = tile * TN;
        const float* xb  = x + (size_t)b * IN_C * HW + ptile;
        __bf16*      xtb = xT + ((size_t)b * HW + ptile) * IN_C;
        int pxq  = tid & 15;
        int rowi = tid >> 4;
        int px   = tid >> 2;
        int icq  = tid & 3;
        for (int chunk = 0; chunk < 4; ++chunk) {
            #pragma unroll
            for (int r = 0; r < 4; ++r) {
                int icL = r * 16 + rowi;
                int ic  = chunk * 64 + icL;
                float4 v = *(const float4*)(xb + (size_t)ic * HW + pxq * 4);
                *(float4*)&tl[icL][pxq * 4] = v;
                float s = v.x + v.y + v.z + v.w;    // f32 pool partial (router accuracy)
                s += __shfl_down(s, 8, 16);
                s += __shfl_down(s, 4, 16);
                s += __shfl_down(s, 2, 16);
                s += __shfl_down(s, 1, 16);
                if (pxq == 0) plsum[ic] = s;
            }
            __syncthreads();
            bf16x8 o0, o1;
            #pragma unroll
            for (int k = 0; k < 8; ++k) o0[k] = (__bf16)tl[icq * 16 + k][px];
            #pragma unroll
            for (int k = 0; k < 8; ++k) o1[k] = (__bf16)tl[icq * 16 + 8 + k][px];
            __bf16* dst = xtb + (size_t)px * IN_C + chunk * 64 + icq * 16;
            *(bf16x8*)dst = o0;
            *(bf16x8*)(dst + 8) = o1;
            __syncthreads();
        }
        partial[(size_t)id * IN_C + tid] = plsum[tid];
    } else {
        int oc = id - NB * NTILE;
        float* sm = smem;
        const float* src = wsrc + (size_t)oc * KTOT;
        #pragma unroll
        for (int k = 0; k < 9; ++k) sm[k * 256 + tid] = src[k * 256 + tid];
        __syncthreads();
        __bf16* dst = wf + (size_t)oc * KTOT;
        for (int C = tid; C < 288; C += 256) {      // 288 chunks of 8 bf16
            int d0  = C * 8;
            int icg = d0 / 288;
            int rem = d0 - icg * 288;
            int tap = rem >> 5, icl0 = rem & 31;
            bf16x8 o;
            #pragma unroll
            for (int j = 0; j < 8; ++j)
                o[j] = (__bf16)sm[(icg * 32 + icl0 + j) * 9 + tap];
            *(bf16x8*)&dst[d0] = o;
        }
    }
}

// ---------------- kernel 2: fused router (redundant, deterministic) + A compaction ------
// 256 blocks = 32 batches x 8 parts. Every block recomputes its batch's routing from
// partial (identical code+data across the 8 duplicates -> bit-identical selection).
// sel/unsel are PREFIX-RANK SORTED (no atomics) so Acomp slot i == sel[i] in every block.
// Ac[b][(g*9+tap)*2048 + oc*32 + icl] bf16: conv af load = contiguous 1KB/wave, L2-hot.
__global__ __launch_bounds__(256) void route_acomp_kernel(const float* __restrict__ partial,
                                                          const float* __restrict__ rw,
                                                          const float* __restrict__ rb,
                                                          const __bf16* __restrict__ wf,
                                                          int* __restrict__ sel,
                                                          int* __restrict__ unsel,
                                                          __bf16* __restrict__ A) {
    int blk = blockIdx.x;
    int b = blk >> 3, part = blk & 7;
    __shared__ float p[IN_C];
    __shared__ float v[OUT_C];
    __shared__ int   fl[OUT_C];
    __shared__ int   sL[NF];
    int t = threadIdx.x;
    {   // pool finalize (coalesced across t)
        float s = 0.f;
        const float* pb = partial + (size_t)b * NTILE * IN_C + t;
        for (int k = 0; k < NTILE; ++k) s += pb[k * IN_C];
        p[t] = s * (1.0f / HW);
    }
    __syncthreads();
    // GEMV: wave w -> oc w*128..+127, coalesced 1KB/wave rw reads + shuffle reduce
    int w = t >> 6, lane = t & 63;
    float4 pl = *(const float4*)&p[lane * 4];
    for (int k = 0; k < 128; ++k) {
        int oc = w * 128 + k;
        float4 wv = *(const float4*)&rw[(size_t)oc * IN_C + lane * 4];
        float d = pl.x * wv.x + pl.y * wv.y + pl.z * wv.z + pl.w * wv.w;
        #pragma unroll
        for (int off = 32; off > 0; off >>= 1) d += __shfl_down(d, off, 64);
        if (lane == 0) v[oc] = d + rb[oc];
    }
    __syncthreads();
    // stable rank (jax top_k tie rule), 2 ocs per thread
    #pragma unroll
    for (int rep = 0; rep < 2; ++rep) {
        int oc = rep * 256 + t;
        float acc = v[oc];
        int cnt = 0;
        for (int j = 0; j < OUT_C; ++j) {
            float o = v[j];
            cnt += (o > acc) || (o == acc && j < oc);
        }
        fl[oc] = (cnt < NF) ? 1 : 0;
    }
    __syncthreads();
    // prefix-rank -> sorted, deterministic positions
    #pragma unroll
    for (int rep = 0; rep < 2; ++rep) {
        int oc = rep * 256 + t;
        int spos = 0;
        for (int j = 0; j < oc; ++j) spos += fl[j];
        if (fl[oc]) {
            sL[spos] = oc;
            if (part == 0) sel[b * NF + spos] = oc;
        } else if (part == 0) {
            unsel[b * NU + (oc - spos)] = oc;
        }
    }
    __syncthreads();
    // A compaction: this part's 9 gt-slices (coalesced writes, 64B-granule L2 reads)
    __bf16* dst = A + (size_t)b * (NF * KTOT);
    #pragma unroll
    for (int c = part * 9; c < part * 9 + 9; ++c) {
        int C = c * 256 + t;                       // C in [0, 18432)
        int icl8 = C & 3, oc = (C >> 2) & 63, gt = C >> 8;
        bf16x8 vv = *(const bf16x8*)&wf[(size_t)sL[oc] * KTOT + gt * 32 + icl8 * 8];
        *(bf16x8*)&dst[(size_t)C * 8] = vv;
    }
}

// ---------------- kernel 3: sparse conv — reg-staged x, af tap-pipeline, 4 blocks/CU ----
// 1568 blocks x 256 thr. Tile M=64 sel-oc x N=64 px. Per group: af depth-1 double-buffer
// (16 VGPR) -> taps; x-slab for g+1 loaded to REGS after all af issues (vmcnt in-order:
// af waits never touch the x loads), ds_write + one barrier. VGPR ~85 -> (256,4).
__global__ __launch_bounds__(256, 4) void conv_kernel(const __bf16* __restrict__ xT,
                                                      const __bf16* __restrict__ Ac,
                                                      const float* __restrict__ bias,
                                                      const int* __restrict__ sel,
                                                      const int* __restrict__ unsel,
                                                      float* __restrict__ out) {
    int id   = blockIdx.x;
    int xcd  = id & 7, slot = id >> 3;          // all 49 tiles of a batch on one XCD
    int bq   = slot / NTILE;
    int tile = slot - bq * NTILE;
    int b    = xcd * 4 + bq;
    int ptile = tile * TN;

    int tid  = threadIdx.x;
    int lane = tid & 63, w = tid >> 6;
    int fm   = lane & 15, fq = lane >> 4;
    int mi2  = w >> 1,  s2 = w & 1;

    __shared__ __bf16 xlds[2][SROWS * 32];      // 2 x 12288 B
    __shared__ int    selLds[NF];

    size_t outb = (size_t)b * OUT_C * HW;
    const __bf16* xtb = xT + (size_t)b * HW * IN_C;
    const __bf16* ab  = Ac + (size_t)b * (NF * KTOT);

    // staging map (round-2 verified): row = rnd*64 + w*16 + (lane>>2);
    // source chunk cc = (lane&3)^((row>>1)&3); LDS chunk = lane&3 (both-sides swizzle)
    const __bf16* sga[3];
    int           srow[3];
    #pragma unroll
    for (int rnd = 0; rnd < 3; ++rnd) {
        int row = rnd * 64 + w * 16 + (lane >> 2);
        int cc  = (lane & 3) ^ ((row >> 1) & 3);
        int gp  = ptile - 57 + row;
        gp = gp < 0 ? 0 : (gp > HW - 1 ? HW - 1 : gp);
        sga[rnd]  = xtb + (size_t)gp * IN_C + cc * 8;
        srow[rnd] = row;
    }

    // ---- prologue: issue x-slab g0 loads first, hide under zero-fill ----
    uint4 xr[3];
    #pragma unroll
    for (int rnd = 0; rnd < 3; ++rnd) xr[rnd] = *(const uint4*)(sga[rnd]);

    if (tid < NF) selLds[tid] = sel[b * NF + tid];

    {   // zero-fill unselected planes (NT stores drain under the K-loop)
        const int* ub = unsel + b * NU;
        f32x4 z = {0.f, 0.f, 0.f, 0.f};
        int lq = tid & 15;
        for (int u = tid >> 4; u < NU; u += 16) {
            int oc = ub[u];
            __builtin_nontemporal_store(z, (f32x4*)(out + outb + (size_t)oc * HW + ptile) + lq);
        }
    }

    #pragma unroll
    for (int rnd = 0; rnd < 3; ++rnd)
        *(uint4*)&xlds[0][srow[rnd] * 32 + (lane & 3) * 8] = xr[rnd];
    __syncthreads();

    const __bf16* pA[2];
    #pragma unroll
    for (int m = 0; m < 2; ++m)
        pA[m] = ab + (size_t)((mi2 * 2 + m) * 16 + fm) * 32 + fq * 8;

    int pp[2], poh[2], pow_[2];
    #pragma unroll
    for (int sl = 0; sl < 2; ++sl) {
        int p = ptile + (s2 * 2 + sl) * 16 + fm;
        pp[sl]   = p;
        poh[sl]  = p / WIDTH;
        pow_[sl] = p - poh[sl] * WIDTH;
    }

    f32x4 acc[2][2] = {};

    #pragma unroll 1
    for (int g = 0; g < NGRP; ++g) {
        int cur = g & 1;
        const size_t gb = (size_t)(g * 9) * 2048;
        bf16x8 afp[2][2];                        // depth-1 af pipeline: 16 VGPR
        afp[0][0] = *(const bf16x8*)(pA[0] + gb);
        afp[0][1] = *(const bf16x8*)(pA[1] + gb);
        #pragma unroll
        for (int t9 = 0; t9 < 9; ++t9) {
            const int pc = t9 & 1;
            if (t9 < 8) {
                afp[pc ^ 1][0] = *(const bf16x8*)(pA[0] + gb + (size_t)(t9 + 1) * 2048);
                afp[pc ^ 1][1] = *(const bf16x8*)(pA[1] + gb + (size_t)(t9 + 1) * 2048);
            }
            const int kr = t9 / 3, kc = t9 - 3 * kr;
            const int shift = (kr - 1) * WIDTH + (kc - 1);
            #pragma unroll
            for (int sl = 0; sl < 2; ++sl) {
                int row = (s2 * 2 + sl) * 16 + fm + 57 + shift;
                int ohr = poh[sl] + kr - 1, owc = pow_[sl] + kc - 1;
                bool ok = ((unsigned)ohr < 56u) && ((unsigned)owc < 56u);
                int sw = fq ^ ((row >> 1) & 3);
                bf16x8 bfr = *(const bf16x8*)&xlds[cur][row * 32 + sw * 8];
                bf16x8 zz = {};
                bfr = ok ? bfr : zz;
                acc[0][sl] = __builtin_amdgcn_mfma_f32_16x16x32_bf16(afp[pc][0], bfr, acc[0][sl], 0, 0, 0);
                acc[1][sl] = __builtin_amdgcn_mfma_f32_16x16x32_bf16(afp[pc][1], bfr, acc[1][sl], 0, 0, 0);
            }
        }
        if (g < NGRP - 1) {
            __builtin_amdgcn_sched_barrier(0);   // pin x-loads below all af issues
            #pragma unroll
            for (int rnd = 0; rnd < 3; ++rnd)
                xr[rnd] = *(const uint4*)(sga[rnd] + (size_t)(g + 1) * 32);
            #pragma unroll
            for (int rnd = 0; rnd < 3; ++rnd)
                *(uint4*)&xlds[cur ^ 1][srow[rnd] * 32 + (lane & 3) * 8] = xr[rnd];
        }
        __syncthreads();
    }

    // epilogue: C/D col = lane&15 (px), row = fq*4 + reg
    #pragma unroll
    for (int m = 0; m < 2; ++m) {
        int mi = mi2 * 2 + m;
        #pragma unroll
        for (int reg = 0; reg < 4; ++reg) {
            int oc = selLds[mi * 16 + fq * 4 + reg];
            float bs = bias[oc];
            float* orow = out + outb + (size_t)oc * HW;
            #pragma unroll
            for (int sl = 0; sl < 2; ++sl)
                __builtin_nontemporal_store(acc[m][sl][reg] + bs, &orow[pp[sl]]);
        }
    }
}

extern "C" void kernel_launch(void* const* d_in, const int* in_sizes, int n_in,
                              void* d_out, int out_size, void* d_ws, size_t ws_size,
                              hipStream_t stream) {
    (void)in_sizes; (void)n_in; (void)ws_size; (void)out_size;
    const float* x        = (const float*)d_in[0];
    const float* weight   = (const float*)d_in[1];
    const float* bias     = (const float*)d_in[2];
    const float* router_w = (const float*)d_in[3];
    const float* router_b = (const float*)d_in[4];
    float* out = (float*)d_out;

    char* ws = (char*)d_ws;
    float*  partial = (float*)ws;                      // 1,605,632 B
    __bf16* wfb     = (__bf16*)(ws + 0x190000);        // 2,359,296 B
    int*    sel     = (int*)(ws + 0x400000);           // 8 KB
    int*    unsel   = (int*)(ws + 0x402000);           // 56 KB
    __bf16* Acomp   = (__bf16*)(ws + 0x410000);        // 9,437,184 B
    __bf16* xT      = (__bf16*)(ws + 0xD10000);        // 51,380,224 B (total ~62.6 MB)

    prep_kernel       <<<NB * NTILE + OUT_C, 256, 0, stream>>>(x, xT, partial, weight, wfb);
    route_acomp_kernel<<<NB * 8,             256, 0, stream>>>(partial, router_w, router_b,
                                                               wfb, sel, unsel, Acomp);
    conv_kernel       <<<NTILE * NB,         256, 0, stream>>>(xT, Acomp, bias, sel, unsel, out);
}

// Round 5
// 407.668 us; speedup vs baseline: 1.1552x; 1.1552x over previous
//
#include <hip/hip_runtime.h>

#define IN_C   256
#define OUT_C  512
#define WIDTH  56
#define HW     3136        // 56*56
#define KTOT   2304        // IN_C*9
#define NF     64
#define NU     448         // OUT_C - NF
#define NB     32
#define NGRP   8           // ic groups of 32
#define TN     64          // pixels per block (3136 = 49*64 exactly -> no tail)
#define NTILE  49
#define XROWS  178         // TN + 2*57 halo
#define LDX    40          // padded LDS row stride (bf16 elems) = 80 B, 16B-aligned

typedef __bf16 bf16x8 __attribute__((ext_vector_type(8)));
typedef float  f32x4  __attribute__((ext_vector_type(4)));

// ---------------- kernel 1: global average pool (R0 champion, verbatim) ----------------
__global__ __launch_bounds__(256) void pool_kernel(const float* __restrict__ x,
                                                   float* __restrict__ pooled) {
    int bc = blockIdx.x;
    const float4* src = (const float4*)(x + (size_t)bc * HW);
    float s = 0.f;
    for (int i = threadIdx.x; i < HW / 4; i += 256) {
        float4 v = src[i];
        s += v.x + v.y + v.z + v.w;
    }
    #pragma unroll
    for (int off = 32; off > 0; off >>= 1) s += __shfl_down(s, off, 64);
    __shared__ float wsum[4];
    int lane = threadIdx.x & 63, wv = threadIdx.x >> 6;
    if (lane == 0) wsum[wv] = s;
    __syncthreads();
    if (threadIdx.x == 0)
        pooled[bc] = (wsum[0] + wsum[1] + wsum[2] + wsum[3]) * (1.0f / HW);
}

// ---------------- kernel 2: router — COALESCED GEMV + ballot prefix compaction ---------
// Only changed kernel vs the 374us champion. Old version: each thread scanned its own
// 1KB rw row (uncoalesced, 64 lines/wave-load) + 256-iter serial dot. New: wave-coalesced
// float4 GEMV (1KB contiguous per wave-load) + shuffle reduce; top-64 via stable rank;
// sel/unsel emitted SORTED via ballot+popcount prefix (no atomics, deterministic).
__global__ __launch_bounds__(512) void router_kernel(const float* __restrict__ pooled,
                                                     const float* __restrict__ rw,
                                                     const float* __restrict__ rb,
                                                     int* __restrict__ sel,
                                                     int* __restrict__ unsel) {
    int b = blockIdx.x;
    __shared__ float p[IN_C];
    __shared__ float v[OUT_C];
    __shared__ int   wcnt[8];
    int t = threadIdx.x;
    if (t < IN_C) p[t] = pooled[b * IN_C + t];
    __syncthreads();
    int w = t >> 6, lane = t & 63;
    float4 pl = *(const float4*)&p[lane * 4];
    for (int k = 0; k < 64; ++k) {                 // wave w -> outputs w*64..w*64+63
        int oc = w * 64 + k;
        float4 wv = *(const float4*)&rw[(size_t)oc * IN_C + lane * 4];  // coalesced 1KB/wave
        float d = pl.x * wv.x + pl.y * wv.y + pl.z * wv.z + pl.w * wv.w;
        #pragma unroll
        for (int off = 32; off > 0; off >>= 1) d += __shfl_down(d, off, 64);
        if (lane == 0) v[oc] = d + rb[oc];
    }
    __syncthreads();
    // stable rank: count strictly-greater, plus equal-with-lower-index (jax top_k tie rule)
    float acc = v[t];
    int cnt = 0;
    for (int j = 0; j < OUT_C; ++j) {
        float o = v[j];
        cnt += (o > acc) || (o == acc && j < t);
    }
    bool isSel = (cnt < NF);
    // ballot-based sorted compaction: spos = #selected with index < t
    unsigned long long m = __ballot(isSel);
    int wrank = __popcll(m & ((1ull << lane) - 1ull));
    if (lane == 0) wcnt[w] = __popcll(m);
    __syncthreads();
    int base = 0;
    #pragma unroll
    for (int i = 0; i < 8; ++i) base += (i < w) ? wcnt[i] : 0;
    int spos = base + wrank;
    if (isSel) sel[b * NF + spos] = t;
    else       unsel[b * NU + (t - spos)] = t;     // #unsel before t = t - spos
}

// ---------------- kernel 3: weight compaction into MFMA-A fragment layout (verbatim) ----
// Acomp[((b*8+g)*9+tap)*64 + oc][32 icl] bf16. blockIdx = b*72 + g*9 + tap.
__global__ __launch_bounds__(256) void compact_w(const float* __restrict__ w,
                                                 const int* __restrict__ sel,
                                                 __bf16* __restrict__ Acomp) {
    int id = blockIdx.x;
    int b = id / 72, rem = id - b * 72;
    int g = rem / 9, tap = rem - g * 9;
    int t = threadIdx.x;
    int oc = t >> 2, q = t & 3;
    int s = sel[b * NF + oc];
    const float* wsrc = w + (size_t)s * KTOT + tap;   // + ic*9
    bf16x8 o;
    #pragma unroll
    for (int j = 0; j < 8; ++j)
        o[j] = (__bf16)wsrc[(g * 32 + q * 8 + j) * 9];
    *(bf16x8*)&Acomp[((size_t)id * 64 + oc) * 32 + q * 8] = o;
}

// ---------------- kernel 4: sparse conv — single-wave blocks, M64xN64 (verbatim) -------
__global__ __launch_bounds__(64) void conv_kernel(const float* __restrict__ x,
                                                  const __bf16* __restrict__ Acomp,
                                                  const float* __restrict__ bias,
                                                  const int* __restrict__ sel,
                                                  const int* __restrict__ unsel,
                                                  float* __restrict__ out) {
    // XCD swizzle: all 49 tiles of a batch land on one XCD -> halo re-reads hit that L2
    int id   = blockIdx.x;
    int xcd  = id & 7, slot = id >> 3;          // slot in [0,196)
    int bq   = slot / NTILE;                    // [0,4)
    int tile = slot - bq * NTILE;
    int b    = xcd * 4 + bq;
    int ptile = tile * TN;

    int lane = threadIdx.x;                     // 0..63
    int fm   = lane & 15, fq = lane >> 4;

    __shared__ __bf16 xlds[XROWS * LDX];        // 14240 B -> up to 11 blocks/CU

    size_t outb = (size_t)b * OUT_C * HW;

    // ---- zero-fill unselected planes (nontemporal, drains under compute) ----
    {
        const int* unselb = unsel + b * NU;
        f32x4 z = {0.f, 0.f, 0.f, 0.f};
        for (int u = fq; u < NU; u += 4) {
            int oc = unselb[u];
            __builtin_nontemporal_store(z, (f32x4*)(out + outb + (size_t)oc * HW + ptile) + fm);
        }
    }

    const float*  x_b    = x + (size_t)b * IN_C * HW;
    const __bf16* a_base = Acomp + (size_t)b * (NGRP * 9 * 64 * 32);

    // output px coords per n-frag (all stores valid: 3136 = 49*64)
    int pp[4], poh[4], pow_[4];
    #pragma unroll
    for (int s = 0; s < 4; ++s) {
        int p = ptile + s * 16 + fm;
        pp[s]   = p;
        poh[s]  = p / WIDTH;
        pow_[s] = p - poh[s] * WIDTH;
    }

    // staging rows: it*64+lane, clamped px (consumers mask invalids via boundary test)
    int gp0[3]; bool act[3];
    #pragma unroll
    for (int it = 0; it < 3; ++it) {
        int sp = it * 64 + lane;
        act[it] = sp < XROWS;
        int gp = ptile - 57 + sp;
        gp = gp < 0 ? 0 : (gp > HW - 1 ? HW - 1 : gp);
        gp0[it] = gp;
    }

    f32x4 acc[4][4] = {};

    #pragma unroll 1
    for (int g = 0; g < NGRP; ++g) {
        // ---- stage group g slab: 178 rows x 32 ic (in-wave ordering, no barrier) ----
        #pragma unroll
        for (int it = 0; it < 3; ++it) {
            if (!act[it]) continue;
            int sp = it * 64 + lane;
            const float* sx = x_b + (size_t)(g * 32) * HW + gp0[it];
            #pragma unroll
            for (int oct = 0; oct < 4; ++oct) {
                float v[8];
                #pragma unroll
                for (int j = 0; j < 8; ++j) v[j] = sx[(size_t)(oct * 8 + j) * HW];
                bf16x8 o;
                #pragma unroll
                for (int j = 0; j < 8; ++j) o[j] = (__bf16)v[j];
                *(bf16x8*)&xlds[sp * LDX + oct * 8] = o;
            }
        }
        // ---- 9 taps ----
        const __bf16* gp_a = a_base + (size_t)g * 9 * 64 * 32;
        #pragma unroll
        for (int t9 = 0; t9 < 9; ++t9) {
            const int r = t9 / 3, c = t9 - 3 * (t9 / 3);
            const int shift = (r - 1) * WIDTH + (c - 1);
            const __bf16* ap = gp_a + (size_t)t9 * 64 * 32;
            bf16x8 af[4];
            #pragma unroll
            for (int mi = 0; mi < 4; ++mi)
                af[mi] = *(const bf16x8*)(ap + (size_t)(mi * 16 + fm) * 32 + fq * 8);
            #pragma unroll
            for (int s = 0; s < 4; ++s) {
                int ohr = poh[s] + r - 1, owc = pow_[s] + c - 1;
                bool ok = ((unsigned)ohr < 56u) && ((unsigned)owc < 56u);
                bf16x8 bfr = *(const bf16x8*)&xlds[(s * 16 + fm + 57 + shift) * LDX + fq * 8];
                bf16x8 zz = {};
                bfr = ok ? bfr : zz;
                #pragma unroll
                for (int mi = 0; mi < 4; ++mi)
                    acc[mi][s] = __builtin_amdgcn_mfma_f32_16x16x32_bf16(af[mi], bfr, acc[mi][s], 0, 0, 0);
            }
        }
    }

    // ---- selected planes: bias + nontemporal store. C/D: col(lane&15)=px, row=fq*4+reg ----
    const int* selb = sel + b * NF;
    #pragma unroll
    for (int mi = 0; mi < 4; ++mi) {
        #pragma unroll
        for (int reg = 0; reg < 4; ++reg) {
            int oc = selb[mi * 16 + fq * 4 + reg];
            float bs = bias[oc];
            float* orow = out + outb + (size_t)oc * HW;
            #pragma unroll
            for (int s = 0; s < 4; ++s)
                __builtin_nontemporal_store(acc[mi][s][reg] + bs, &orow[pp[s]]);
        }
    }
}

extern "C" void kernel_launch(void* const* d_in, const int* in_sizes, int n_in,
                              void* d_out, int out_size, void* d_ws, size_t ws_size,
                              hipStream_t stream) {
    (void)in_sizes; (void)n_in; (void)ws_size; (void)out_size;
    const float* x        = (const float*)d_in[0];
    const float* weight   = (const float*)d_in[1];
    const float* bias     = (const float*)d_in[2];
    const float* router_w = (const float*)d_in[3];
    const float* router_b = (const float*)d_in[4];
    float* out = (float*)d_out;

    char* ws = (char*)d_ws;
    float*  pooled = (float*)ws;                       // 32 KB
    int*    sel    = (int*)(ws + 32768);               // 8 KB
    int*    unsel  = (int*)(ws + 40960);               // 56 KB
    __bf16* Acomp  = (__bf16*)(ws + 131072);           // 9.44 MB

    pool_kernel<<<NB * IN_C, 256, 0, stream>>>(x, pooled);
    router_kernel<<<NB, OUT_C, 0, stream>>>(pooled, router_w, router_b, sel, unsel);
    compact_w<<<NB * NGRP * 9, 256, 0, stream>>>(weight, sel, Acomp);

    conv_kernel<<<NTILE * NB, 64, 0, stream>>>(x, Acomp, bias, sel, unsel, out);
}